// Round 13
// baseline (144.265 us; speedup 1.0000x reference)
//
#include <hip/hip_runtime.h>

#define HH 256
#define WW 256
#define NPIX (2 * HH * WW)   // 131072 (B=2)
#define NC 48
#define NB 31
#define NG 6          // channel groups
#define CG 8          // channels per group (NG*CG == NC)
#define OT 32         // output tile (32x32 per block)
#define PT 38         // phi tile = OT+6
#define PSTR 44       // phi LDS row stride (16B aligned)
#define UT 44         // u tile = OT+12
#define USTR 52       // u LDS row stride (16B aligned)
#define TM 385        // phi-table points per channel, x in [-1.5,1.5], h=3/384
#define TSTR 386      // table stride (incl. lerp guard entry)
#define NTILE 128     // 8x8 tiles x B=2
// ws layout (floats): acc[NPIX] | cnt[NTILE] | tab[NC*TSTR]
#define CNT_OFF  NPIX
#define TAB_OFF  (NPIX + NTILE)     // 131200: *4B = 16B-aligned

// ---- Build the 48 phi tables once: tab[c][j], j=0..385 (386 incl. guard).
__global__ __launch_bounds__(256)
void tnrd_table(const float* __restrict__ wr, float* __restrict__ tab)
{
    const int ch = blockIdx.x;
    const float* rc = wr + ch * NB;
    for (int j = threadIdx.x; j < TSTR; j += 256) {
        float x = fmaf((float)j, 3.0f / 384.0f, -1.5f);
        float s = 0.f;
        #pragma unroll
        for (int k = 0; k < NB; ++k) {
            float mu = -1.f + (float)k * (1.f / 15.f);
            float d = x - mu;
            s = fmaf(rc[k], __expf(-50.f * d * d), s);
        }
        tab[ch * TSTR + j] = s;
    }
}

// Fused: conv1(7x7, 2ch/pass, SW-pipelined dy) -> table-lerp RBF ->
// conv2(flipped 7x7, 2ch/pass) with cross-pass phi double-buffering
// (r12 hot loop, byte-identical), PLUS fused combine: blocks atomicAdd
// partials into acc; last block per tile (threadfence+counter protocol)
// reads back via coherent atomic RMW and writes the final output.
// Hard-won constraints (do not violate):
//  - all per-lane accumulators NAMED SCALARS (r3: arrays -> 700 MB spill)
//  - 2 channels/pass, dy loop unroll-pinned (r5: 4ch+unroll -> VALU +40%)
//  - 4-px items, 12-float window (r6: 8-px items -> 300 MB spill)
//  - gather conflicts are data-dependent (r9/r11) — not fixable by layout
//  - more blocks/CU does not help (r10): waves stall in phase
__global__ __launch_bounds__(256, 3)
void tnrd_main(const float* __restrict__ u,
               const float* __restrict__ fimg,
               const float* __restrict__ lam,
               const float* __restrict__ wf,    // filters [48][49]
               const float* __restrict__ tab,   // phi tables [48][TSTR] (ws)
               float* __restrict__ acc,         // [NPIX] zeroed accumulator
               unsigned* __restrict__ cnt,      // [NTILE] zeroed counters
               float* __restrict__ outp)
{
    __shared__ __align__(16) float u_s[UT * USTR];          //  9152 B
    __shared__ __align__(16) float phi_s[4][PT * PSTR];     // 26752 B
    __shared__ __align__(16) float tabs[CG][TSTR];          // 12352 B
    __shared__ int last_flag;

    const int tid = threadIdx.x;
    const int bx = blockIdx.x, by = blockIdx.y;
    const int b = blockIdx.z / NG, g = blockIdx.z % NG;
    const int c0g = g * CG;

    // ---- stage u tile (6-halo, zero-padded incl. stride pad) ----
    const int uy0 = by * OT - 6, ux0 = bx * OT - 6;
    const float* ub = u + b * (HH * WW);
    for (int i = tid; i < UT * USTR; i += 256) {
        int r = i / USTR, c = i - r * USTR;
        int gy = uy0 + r, gx = ux0 + c;
        float v = 0.f;
        if (c < UT && (unsigned)gy < HH && (unsigned)gx < WW)
            v = ub[gy * WW + gx];
        u_s[i] = v;
    }

    // ---- stage this group's 8 tables: 3088 floats = 772 float4 (L2-hit) ----
    {
        const float4* src = (const float4*)(tab + c0g * TSTR);
        float4* dst = (float4*)&tabs[0][0];
        #pragma unroll 1   // r8: unrolling this copy pushed VGPR 64->84 + spill
        for (int i = tid; i < CG * TSTR / 4; i += 256) dst[i] = src[i];
    }

    const int oy = tid >> 3;        // 0..31
    const int ox0 = (tid & 7) * 4;  // 0..28
    float o0 = 0.f, o1 = 0.f, o2 = 0.f, o3 = 0.f;
    const int py0 = by * OT - 3, px0 = bx * OT - 3;

    // ---- conv1 + RBF lerp for channel pair cp into planes bufA/bufB ----
    auto conv1_pass = [&](int cp, float* __restrict__ bufA,
                          float* __restrict__ bufB) {
        const float* wA = wf + (c0g + 2 * cp) * 49;   // block-uniform s_load
        const float* wB = wA + 49;
        const float* tA = tabs[2 * cp];
        const float* tB = tabs[2 * cp + 1];
        // 380 items = 10 col-strips x 38 rows (column-major)
        for (int p = 0; p < 2; ++p) {
            const int gi = tid + p * 256;
            if (gi < PT * 10) {
                const int pr = gi % PT, pc = (gi / PT) * 4;
                float a0 = 0.f, a1 = 0.f, a2 = 0.f, a3 = 0.f;
                float b0 = 0.f, b1 = 0.f, b2 = 0.f, b3 = 0.f;
                const float* bptr = &u_s[pr * USTR + pc];

                auto fmab = [&](const float* wa, const float* wb,
                                float4 q0, float4 q1, float4 q2) {
                    float sv[12] = {q0.x, q0.y, q0.z, q0.w,
                                    q1.x, q1.y, q1.z, q1.w,
                                    q2.x, q2.y, q2.z, q2.w};
                    #pragma unroll
                    for (int dx = 0; dx < 7; ++dx) {
                        float fa = wa[dx], fb = wb[dx];
                        a0 = fmaf(sv[dx],     fa, a0);
                        a1 = fmaf(sv[dx + 1], fa, a1);
                        a2 = fmaf(sv[dx + 2], fa, a2);
                        a3 = fmaf(sv[dx + 3], fa, a3);
                        b0 = fmaf(sv[dx],     fb, b0);
                        b1 = fmaf(sv[dx + 1], fb, b1);
                        b2 = fmaf(sv[dx + 2], fb, b2);
                        b3 = fmaf(sv[dx + 3], fb, b3);
                    }
                };

                // software pipeline: load row dy+1 before consuming row dy
                float4 c0 = *(const float4*)(bptr);
                float4 c1 = *(const float4*)(bptr + 4);
                float4 c2 = *(const float4*)(bptr + 8);
                #pragma unroll 1
                for (int dy = 0; dy < 6; ++dy) {
                    const float* nr = bptr + (dy + 1) * USTR;
                    float4 n0 = *(const float4*)(nr);
                    float4 n1 = *(const float4*)(nr + 4);
                    float4 n2 = *(const float4*)(nr + 8);
                    fmab(wA + dy * 7, wB + dy * 7, c0, c1, c2);
                    c0 = n0; c1 = n1; c2 = n2;
                }
                fmab(wA + 42, wB + 42, c0, c1, c2);   // epilogue dy=6

                // ---- table lerp; phi = 0 outside image (conv2 zero-pad) ----
                const int gy = py0 + pr;
                const bool rowok = (unsigned)gy < HH;
                float av[4] = {a0, a1, a2, a3};
                float bv[4] = {b0, b1, b2, b3};
                float pha[4], phb[4];
                #pragma unroll
                for (int j = 0; j < 4; ++j) {
                    bool ok = rowok && (unsigned)(px0 + pc + j) < WW;
                    float ta = fminf(fmaxf(fmaf(av[j], 128.f, 192.f), 0.f), 383.999f);
                    float fja = floorf(ta);
                    int ia = (int)fja;
                    float va = fmaf(ta - fja, tA[ia + 1] - tA[ia], tA[ia]);
                    float tb = fminf(fmaxf(fmaf(bv[j], 128.f, 192.f), 0.f), 383.999f);
                    float fjb = floorf(tb);
                    int ib = (int)fjb;
                    float vb = fmaf(tb - fjb, tB[ib + 1] - tB[ib], tB[ib]);
                    pha[j] = ok ? va : 0.f;
                    phb[j] = ok ? vb : 0.f;
                }
                float* dA = bufA + pr * PSTR + pc;
                float* dB = bufB + pr * PSTR + pc;
                #pragma unroll
                for (int j = 0; j < 4; ++j) dA[j] = pha[j];  // ds_write_b128
                #pragma unroll
                for (int j = 0; j < 4; ++j) dB[j] = phb[j];  // ds_write_b128
            }
        }
    };

    // prologue: pass 0 -> planes {0,1}; the sync also covers u_s/tabs staging
    conv1_pass(0, phi_s[0], phi_s[1]);
    __syncthreads();

    #pragma unroll 1
    for (int pass = 0; pass < 4; ++pass) {
        if (pass < 3) {
            const int nb_ = (pass + 1) & 1;
            conv1_pass(pass + 1, phi_s[2 * nb_], phi_s[2 * nb_ + 1]);
        }

        // ---- conv2 accumulate pass's two channels (flipped weights) ----
        const float* wA = wf + (c0g + 2 * pass) * 49;
        const float* wB = wA + 49;
        const float* pA = phi_s[2 * (pass & 1)];
        const float* pB = phi_s[2 * (pass & 1) + 1];
        for (int dy = 0; dy < 7; ++dy) {
            const float* rA = pA + (oy + dy) * PSTR + ox0;
            const float* rB = pB + (oy + dy) * PSTR + ox0;
            float sa[10], sb[10];
            #pragma unroll
            for (int j = 0; j < 10; ++j) sa[j] = rA[j];
            #pragma unroll
            for (int j = 0; j < 10; ++j) sb[j] = rB[j];
            #pragma unroll
            for (int dx = 0; dx < 7; ++dx) {
                float fa = wA[(6 - dy) * 7 + (6 - dx)];
                float fb = wB[(6 - dy) * 7 + (6 - dx)];
                o0 = fmaf(sa[dx],     fa, o0);
                o1 = fmaf(sa[dx + 1], fa, o1);
                o2 = fmaf(sa[dx + 2], fa, o2);
                o3 = fmaf(sa[dx + 3], fa, o3);
                o0 = fmaf(sb[dx],     fb, o0);
                o1 = fmaf(sb[dx + 1], fb, o1);
                o2 = fmaf(sb[dx + 2], fb, o2);
                o3 = fmaf(sb[dx + 3], fb, o3);
            }
        }
        if (pass < 3) __syncthreads();
    }

    // ---- fused combine: accumulate, then last block per tile finishes ----
    const int gy = by * OT + oy, gx = bx * OT + ox0;
    const int base = b * (HH * WW) + gy * WW + gx;
    atomicAdd(&acc[base + 0], o0);    // device-scope by default (G12)
    atomicAdd(&acc[base + 1], o1);
    atomicAdd(&acc[base + 2], o2);
    atomicAdd(&acc[base + 3], o3);
    __threadfence();                  // adds globally visible before counter
    __syncthreads();                  // all threads' adds+fences done
    if (tid == 0) {
        unsigned old = atomicAdd(&cnt[b * 64 + by * 8 + bx], 1u);
        last_flag = (old == NG - 1) ? 1 : 0;
    }
    __syncthreads();
    if (last_flag) {
        __threadfence();
        float lv = lam[0];
        float4 uv4 = *(const float4*)(u + base);
        float4 fv4 = *(const float4*)(fimg + base);
        // coherent readback via atomic RMW (plain loads could hit a stale
        // per-XCD L2 line — G16); returns the current accumulated value
        float d0 = atomicAdd(&acc[base + 0], 0.f);
        float d1 = atomicAdd(&acc[base + 1], 0.f);
        float d2 = atomicAdd(&acc[base + 2], 0.f);
        float d3 = atomicAdd(&acc[base + 3], 0.f);
        float4 r;
        r.x = uv4.x - d0 - lv * (uv4.x - fv4.x);
        r.y = uv4.y - d1 - lv * (uv4.y - fv4.y);
        r.z = uv4.z - d2 - lv * (uv4.z - fv4.z);
        r.w = uv4.w - d3 - lv * (uv4.w - fv4.w);
        *(float4*)(outp + base) = r;
    }
}

extern "C" void kernel_launch(void* const* d_in, const int* in_sizes, int n_in,
                              void* d_out, int out_size, void* d_ws, size_t ws_size,
                              hipStream_t stream) {
    const float* u    = (const float*)d_in[0];
    const float* f    = (const float*)d_in[1];
    const float* filt = (const float*)d_in[2];
    const float* rbfw = (const float*)d_in[3];
    const float* lam  = (const float*)d_in[4];
    float* out = (float*)d_out;
    float* ws  = (float*)d_ws;
    float*    acc  = ws;                          // [NPIX]
    unsigned* cnt  = (unsigned*)(ws + CNT_OFF);   // [NTILE]
    float*    tabg = ws + TAB_OFF;                // [NC*TSTR]

    // zero accumulator + tile counters (graph-capture-safe async memset)
    hipMemsetAsync(d_ws, 0, (size_t)(NPIX + NTILE) * sizeof(float), stream);
    tnrd_table<<<NC, 256, 0, stream>>>(rbfw, tabg);
    tnrd_main<<<dim3(8, 8, 2 * NG), 256, 0, stream>>>(u, f, lam, filt, tabg,
                                                      acc, cnt, out);
}

// Round 14
// 109.029 us; speedup vs baseline: 1.3232x; 1.3232x over previous
//
#include <hip/hip_runtime.h>

#define HH 256
#define WW 256
#define NPIX (2 * HH * WW)   // 131072 (B=2)
#define NC 48
#define NB 31
#define NG 6          // channel groups
#define CG 8          // channels per group (NG*CG == NC)
#define OT 32         // output tile (32x32 per block)
#define PT 38         // phi tile = OT+6
#define PSTR 44       // phi LDS row stride (16B aligned)
#define UT 44         // u tile = OT+12
#define USTR 52       // u LDS row stride (16B aligned)
#define TP 192        // table pairs per channel: x in [-1.5,1.5], h=1/64

// ---- Build the 48 phi tables once as (value, delta) pairs for 1-read lerp.
__global__ __launch_bounds__(256)
void tnrd_table(const float* __restrict__ wr, float2* __restrict__ tab)
{
    const int ch = blockIdx.x;
    const float* rc = wr + ch * NB;
    for (int j = threadIdx.x; j < TP; j += 256) {
        float v0 = 0.f, v1 = 0.f;
        float x0 = fmaf((float)j, 1.0f / 64.0f, -1.5f);
        float x1 = x0 + 1.0f / 64.0f;
        #pragma unroll
        for (int k = 0; k < NB; ++k) {
            float mu = -1.f + (float)k * (1.f / 15.f);
            float d0 = x0 - mu, d1 = x1 - mu;
            float w = rc[k];
            v0 = fmaf(w, __expf(-50.f * d0 * d0), v0);
            v1 = fmaf(w, __expf(-50.f * d1 * d1), v1);
        }
        tab[ch * TP + j] = make_float2(v0, v1 - v0);
    }
}

// Fused: conv1(7x7, 2ch/pass, SW-pipelined dy) -> table-lerp RBF ->
// conv2(flipped 7x7, 2ch/pass) with cross-pass phi double-buffering
// (r12 hot loop). r14 delta: table is float2 (value, delta) -> ONE
// ds_read_b64 gather per lerp instead of two dependent ds_read_b32
// (r12: 9.67e6 conflict cycles ~= 15 us/CU, half of the LDS pipe).
// Hard-won constraints (do not violate):
//  - all per-lane accumulators NAMED SCALARS (r3: arrays -> 700 MB spill)
//  - 2 channels/pass, dy loop unroll-pinned (r5: 4ch+unroll -> VALU +40%)
//  - 4-px items, 12-float window (r6: 8-px items -> 300 MB spill)
//  - more blocks/CU does not help (r10); atomic combine is a 34 us loss (r13)
__global__ __launch_bounds__(256, 3)
void tnrd_main(const float* __restrict__ u,
               const float* __restrict__ wf,    // filters [48][49]
               const float2* __restrict__ tab,  // phi tables [48][TP]
               float* __restrict__ part)
{
    __shared__ __align__(16) float u_s[UT * USTR];          //  9152 B
    __shared__ __align__(16) float phi_s[4][PT * PSTR];     // 26752 B
    __shared__ __align__(16) float2 tabs[CG][TP];           // 12288 B

    const int tid = threadIdx.x;
    const int bx = blockIdx.x, by = blockIdx.y;
    const int b = blockIdx.z / NG, g = blockIdx.z % NG;
    const int c0g = g * CG;

    // ---- stage u tile (6-halo, zero-padded incl. stride pad) ----
    const int uy0 = by * OT - 6, ux0 = bx * OT - 6;
    const float* ub = u + b * (HH * WW);
    for (int i = tid; i < UT * USTR; i += 256) {
        int r = i / USTR, c = i - r * USTR;
        int gy = uy0 + r, gx = ux0 + c;
        float v = 0.f;
        if (c < UT && (unsigned)gy < HH && (unsigned)gx < WW)
            v = ub[gy * WW + gx];
        u_s[i] = v;
    }

    // ---- stage this group's 8 tables: 12288 B = 768 float4 (L2-hit) ----
    {
        const float4* src = (const float4*)(tab + c0g * TP);
        float4* dst = (float4*)&tabs[0][0];
        #pragma unroll 1   // r8: unrolling this copy pushed VGPR 64->84 + spill
        for (int i = tid; i < CG * TP / 2; i += 256) dst[i] = src[i];
    }

    const int oy = tid >> 3;        // 0..31
    const int ox0 = (tid & 7) * 4;  // 0..28
    float o0 = 0.f, o1 = 0.f, o2 = 0.f, o3 = 0.f;
    const int py0 = by * OT - 3, px0 = bx * OT - 3;

    // ---- conv1 + RBF lerp for channel pair cp into planes bufA/bufB ----
    auto conv1_pass = [&](int cp, float* __restrict__ bufA,
                          float* __restrict__ bufB) {
        const float* wA = wf + (c0g + 2 * cp) * 49;   // block-uniform s_load
        const float* wB = wA + 49;
        const float2* tA = tabs[2 * cp];
        const float2* tB = tabs[2 * cp + 1];
        // 380 items = 10 col-strips x 38 rows (column-major)
        for (int p = 0; p < 2; ++p) {
            const int gi = tid + p * 256;
            if (gi < PT * 10) {
                const int pr = gi % PT, pc = (gi / PT) * 4;
                float a0 = 0.f, a1 = 0.f, a2 = 0.f, a3 = 0.f;
                float b0 = 0.f, b1 = 0.f, b2 = 0.f, b3 = 0.f;
                const float* bptr = &u_s[pr * USTR + pc];

                auto fmab = [&](const float* wa, const float* wb,
                                float4 q0, float4 q1, float4 q2) {
                    float sv[12] = {q0.x, q0.y, q0.z, q0.w,
                                    q1.x, q1.y, q1.z, q1.w,
                                    q2.x, q2.y, q2.z, q2.w};
                    #pragma unroll
                    for (int dx = 0; dx < 7; ++dx) {
                        float fa = wa[dx], fb = wb[dx];
                        a0 = fmaf(sv[dx],     fa, a0);
                        a1 = fmaf(sv[dx + 1], fa, a1);
                        a2 = fmaf(sv[dx + 2], fa, a2);
                        a3 = fmaf(sv[dx + 3], fa, a3);
                        b0 = fmaf(sv[dx],     fb, b0);
                        b1 = fmaf(sv[dx + 1], fb, b1);
                        b2 = fmaf(sv[dx + 2], fb, b2);
                        b3 = fmaf(sv[dx + 3], fb, b3);
                    }
                };

                // software pipeline: load row dy+1 before consuming row dy
                float4 c0 = *(const float4*)(bptr);
                float4 c1 = *(const float4*)(bptr + 4);
                float4 c2 = *(const float4*)(bptr + 8);
                #pragma unroll 1
                for (int dy = 0; dy < 6; ++dy) {
                    const float* nr = bptr + (dy + 1) * USTR;
                    float4 n0 = *(const float4*)(nr);
                    float4 n1 = *(const float4*)(nr + 4);
                    float4 n2 = *(const float4*)(nr + 8);
                    fmab(wA + dy * 7, wB + dy * 7, c0, c1, c2);
                    c0 = n0; c1 = n1; c2 = n2;
                }
                fmab(wA + 42, wB + 42, c0, c1, c2);   // epilogue dy=6

                // ---- 1-gather lerp; phi = 0 outside image (conv2 zero-pad) ----
                const int gy = py0 + pr;
                const bool rowok = (unsigned)gy < HH;
                float av[4] = {a0, a1, a2, a3};
                float bv[4] = {b0, b1, b2, b3};
                float pha[4], phb[4];
                #pragma unroll
                for (int j = 0; j < 4; ++j) {
                    bool ok = rowok && (unsigned)(px0 + pc + j) < WW;
                    float ta = fminf(fmaxf(fmaf(av[j], 64.f, 96.f), 0.f), 191.999f);
                    float fja = floorf(ta);
                    float2 ea = tA[(int)fja];            // ds_read_b64 gather
                    float va = fmaf(ta - fja, ea.y, ea.x);
                    float tb = fminf(fmaxf(fmaf(bv[j], 64.f, 96.f), 0.f), 191.999f);
                    float fjb = floorf(tb);
                    float2 eb = tB[(int)fjb];            // ds_read_b64 gather
                    float vb = fmaf(tb - fjb, eb.y, eb.x);
                    pha[j] = ok ? va : 0.f;
                    phb[j] = ok ? vb : 0.f;
                }
                float* dA = bufA + pr * PSTR + pc;
                float* dB = bufB + pr * PSTR + pc;
                #pragma unroll
                for (int j = 0; j < 4; ++j) dA[j] = pha[j];  // ds_write_b128
                #pragma unroll
                for (int j = 0; j < 4; ++j) dB[j] = phb[j];  // ds_write_b128
            }
        }
    };

    // prologue: pass 0 -> planes {0,1}; the sync also covers u_s/tabs staging
    conv1_pass(0, phi_s[0], phi_s[1]);
    __syncthreads();

    #pragma unroll 1
    for (int pass = 0; pass < 4; ++pass) {
        if (pass < 3) {
            const int nb_ = (pass + 1) & 1;
            conv1_pass(pass + 1, phi_s[2 * nb_], phi_s[2 * nb_ + 1]);
        }

        // ---- conv2 accumulate pass's two channels (flipped weights) ----
        const float* wA = wf + (c0g + 2 * pass) * 49;
        const float* wB = wA + 49;
        const float* pA = phi_s[2 * (pass & 1)];
        const float* pB = phi_s[2 * (pass & 1) + 1];
        for (int dy = 0; dy < 7; ++dy) {
            const float* rA = pA + (oy + dy) * PSTR + ox0;
            const float* rB = pB + (oy + dy) * PSTR + ox0;
            float sa[10], sb[10];
            #pragma unroll
            for (int j = 0; j < 10; ++j) sa[j] = rA[j];
            #pragma unroll
            for (int j = 0; j < 10; ++j) sb[j] = rB[j];
            #pragma unroll
            for (int dx = 0; dx < 7; ++dx) {
                float fa = wA[(6 - dy) * 7 + (6 - dx)];
                float fb = wB[(6 - dy) * 7 + (6 - dx)];
                o0 = fmaf(sa[dx],     fa, o0);
                o1 = fmaf(sa[dx + 1], fa, o1);
                o2 = fmaf(sa[dx + 2], fa, o2);
                o3 = fmaf(sa[dx + 3], fa, o3);
                o0 = fmaf(sb[dx],     fb, o0);
                o1 = fmaf(sb[dx + 1], fb, o1);
                o2 = fmaf(sb[dx + 2], fb, o2);
                o3 = fmaf(sb[dx + 3], fb, o3);
            }
        }
        if (pass < 3) __syncthreads();
    }

    const int gy = by * OT + oy, gx = bx * OT + ox0;
    float4 v4 = make_float4(o0, o1, o2, o3);
    *reinterpret_cast<float4*>(part + (size_t)g * NPIX + b * (HH * WW)
                               + gy * WW + gx) = v4;
}

__global__ __launch_bounds__(256)
void combine_kernel(const float* __restrict__ u,
                    const float* __restrict__ f,
                    const float* __restrict__ lam,
                    const float* __restrict__ part,
                    float* __restrict__ out)
{
    int i = blockIdx.x * 256 + threadIdx.x;  // 512 blocks -> NPIX
    float d = 0.f;
    #pragma unroll
    for (int g = 0; g < NG; ++g) d += part[g * NPIX + i];
    float lv = lam[0];
    float uv = u[i];
    float fv = f[i];
    out[i] = uv - d - lv * (uv - fv);
}

extern "C" void kernel_launch(void* const* d_in, const int* in_sizes, int n_in,
                              void* d_out, int out_size, void* d_ws, size_t ws_size,
                              hipStream_t stream) {
    const float* u    = (const float*)d_in[0];
    const float* f    = (const float*)d_in[1];
    const float* filt = (const float*)d_in[2];
    const float* rbfw = (const float*)d_in[3];
    const float* lam  = (const float*)d_in[4];
    float* out = (float*)d_out;
    float* part = (float*)d_ws;   // 6 * 131072 f32 partial sums (3.1 MB)
    // phi tables overlaid on d_out scratch (48*192 float2 = 18432 floats
    // <= 131072); combine_kernel fully overwrites d_out afterwards.
    float2* tabg = (float2*)d_out;

    tnrd_table<<<NC, 256, 0, stream>>>(rbfw, tabg);
    tnrd_main<<<dim3(8, 8, 2 * NG), 256, 0, stream>>>(u, filt, tabg, part);
    combine_kernel<<<512, 256, 0, stream>>>(u, f, lam, part, out);
}